// Round 11
// baseline (48.849 us; speedup 1.0000x reference)
//
#include <hip/hip_runtime.h>

#define SN 128
#define SPK 512

constexpr float GMIN  = 0.1f;
constexpr float PFRAC = 0.3f;
constexpr float GMAX  = 1.0f;

// Fill + scatter formulation.
// Lazy decay: v(n) = C(n)*a + GMIN, C(n) = exp((ts0-ts[n])/TAU) <= 1.
// Untouched cell: a = -GMIN -> u_r = GMIN*(1-C(n_r)) identical for all cells.
// Touch at step t: a' = 0.7*a + 0.27/C(t) (init event at t=0: a = 0.17).
// Monotonicity: at fixed snapshot time, value over prefix P1 subset P2 satisfies
// v(P1) <= v(P2)  =>  atomicMax over per-touch own-prefix candidates is exact.
// K1: per-sample n_last[8], C_r, u_r -> ws.   K2: fill out with u_{s,r}.
// K3: one thread per event; LDS hash flags same-cell duplicates (slow path
// compounds predecessors); 8 gated atomicMax into pooled output.

// ---------------- K1: per-sample snapshot table ----------------
__global__ __launch_bounds__(64, 4) void prep_kernel(
    const float* __restrict__ ts,      // (SN, SPK)
    const int*   __restrict__ tt,      // (SN, SPK)
    int*         __restrict__ wsNl,    // (SN*8)
    float*       __restrict__ wsC,     // (SN*8)
    float*       __restrict__ wsU)     // (SN*8)
{
    const int s    = blockIdx.x;
    const int lane = threadIdx.x;

    const float ts0 = ts[s * SPK];

    int tv[8];
#pragma unroll
    for (int r8 = 0; r8 < 8; ++r8)
        tv[r8] = tt[s * SPK + r8 * 64 + lane];

    // last occurrence of each slot at n>=1 (reverse scan, uniform early-exit)
    int snl[8];
#pragma unroll
    for (int r = 0; r < 8; ++r) {
        int f = -1;
#pragma unroll
        for (int rr = 7; rr >= 0; --rr) {
            if (f < 0) {
                unsigned long long m =
                    __ballot(tv[rr] == r && (rr > 0 || lane > 0));
                if (m) f = rr * 64 + 63 - __clzll(m);
            }
        }
        snl[r] = f;
    }

    if (lane < 8) {
        int nr = snl[0];
#pragma unroll
        for (int r = 1; r < 8; ++r) nr = (lane == r) ? snl[r] : nr;
        if (lane == 0 && nr < 0) nr = 0;      // slot0 missing -> init state at t=0
        float C = 0.0f, u = 0.0f;
        if (nr >= 0) {
            float tsn = ts[s * SPK + nr];
            C = (nr == 0) ? 1.0f : __expf((ts0 - tsn) * 0.01f);   // TAU=100
            u = fmaf(C, -GMIN, GMIN);
        }
        wsNl[s * 8 + lane] = nr;
        wsC [s * 8 + lane] = C;
        wsU [s * 8 + lane] = u;
    }
}

// ---------------- K2: broadcast fill ----------------
__global__ __launch_bounds__(256) void fill_kernel(
    const float* __restrict__ wsU,
    float*       __restrict__ out)
{
    const int total4 = SN * 8 * 2 * 64 * 64 / 4;       // 2,097,152 float4
    float4* o4 = reinterpret_cast<float4*>(out);
    for (int idx = blockIdx.x * 256 + threadIdx.x; idx < total4;
         idx += gridDim.x * 256) {
        float u = wsU[idx >> 11];                      // 2048 float4 per (s,r)
        o4[idx] = make_float4(u, u, u, u);
    }
}

// ---------------- K3: per-event scatter with atomicMax ----------------
#define HBITS 12
#define HSIZE (1 << HBITS)

__global__ __launch_bounds__(512, 2) void scatter_kernel(
    const int*   __restrict__ event,   // (SN, SPK, 3)
    const float* __restrict__ ts,      // (SN, SPK)
    const int*   __restrict__ length,  // (SN,)
    const int*   __restrict__ wsNl,
    const float* __restrict__ wsC,
    float*       __restrict__ out)
{
    __shared__ unsigned hcnt[HSIZE];   // 16 KB
    __shared__ unsigned skey[SPK];     // 2 KB  (key or ~0u if gated)
    __shared__ float    stsn[SPK];     // 2 KB

    const int s = blockIdx.x;
    const int n = threadIdx.x;         // event index 0..511

    const int   len = length[s];
    const float ts0 = ts[s * SPK];

    // load my event
    const int* ev = event + (size_t)(s * SPK + n) * 3;
    int ex = ev[0], ey = ev[1], ep = ev[2];
    float tsn = ts[s * SPK + n];
    unsigned key = (unsigned)((ep << 14) | (ex << 7) | ey);
    bool gate = (n < len);             // is a touch (n==0 init always: len>=1)

    // stage LDS
    skey[n] = gate ? key : 0xFFFFFFFFu;
    stsn[n] = tsn;
#pragma unroll
    for (int k = 0; k < HSIZE / SPK; ++k) hcnt[n + k * SPK] = 0u;
    __syncthreads();

    unsigned h = (key * 2654435761u) >> (32 - HBITS);
    if (gate) atomicAdd(&hcnt[h], 1u);
    __syncthreads();

    if (!gate) return;

    // own-prefix amplitude
    float Ce = (n == 0) ? 1.0f : __expf((ts0 - tsn) * 0.01f);
    float a;
    if (hcnt[h] > 1u) {                // possible same-cell predecessors (rare)
        a = -GMIN;
        for (int j = 0; j < n; ++j) {
            if (skey[j] == key) {
                if (j == 0) {
                    a = PFRAC * (GMAX - GMIN) - GMIN;            // 0.17
                } else {
                    float Cj = __expf((ts0 - stsn[j]) * 0.01f);
                    a = fmaf(1.0f - PFRAC, a, PFRAC * (GMAX - GMIN) / Cj);
                }
            }
        }
        a = (n == 0) ? (PFRAC * (GMAX - GMIN) - GMIN)
                     : fmaf(1.0f - PFRAC, a, PFRAC * (GMAX - GMIN) / Ce);
    } else {                           // single touch on this cell
        a = (n == 0) ? (PFRAC * (GMAX - GMIN) - GMIN)
                     : fmaf(1.0f - PFRAC, -GMIN, PFRAC * (GMAX - GMIN) / Ce);
    }

    // scatter to the 8 snapshots (t_e <= n_r)
    const int Xo = ex >> 1, Yo = ey >> 1;
    int* oi = reinterpret_cast<int*>(out);
#pragma unroll
    for (int r = 0; r < 8; ++r) {
        int   nr = wsNl[s * 8 + r];
        float Cr = wsC [s * 8 + r];
        if (n <= nr) {
            float val = fmaf(Cr, a, GMIN);           // >= 0 always
            int   idx = (((s * 8 + r) * 2 + ep) * 64 + Xo) * 64 + Yo;
            atomicMax(oi + idx, __float_as_int(val));
        }
    }
}

extern "C" void kernel_launch(void* const* d_in, const int* in_sizes, int n_in,
                              void* d_out, int out_size, void* d_ws, size_t ws_size,
                              hipStream_t stream) {
    const int*   event  = (const int*)  d_in[0];
    const float* ts     = (const float*)d_in[1];
    const int*   tt     = (const int*)  d_in[2];
    const int*   length = (const int*)  d_in[3];
    float*       out    = (float*)d_out;

    int*   wsNl = (int*)d_ws;                  // SN*8 ints
    float* wsC  = (float*)(wsNl + SN * 8);     // SN*8 floats
    float* wsU  = wsC + SN * 8;                // SN*8 floats

    prep_kernel   <<<dim3(SN),   dim3(64),  0, stream>>>(ts, tt, wsNl, wsC, wsU);
    fill_kernel   <<<dim3(2048), dim3(256), 0, stream>>>(wsU, out);
    scatter_kernel<<<dim3(SN),   dim3(512), 0, stream>>>(event, ts, length,
                                                         wsNl, wsC, out);
}

// Round 12
// 28.426 us; speedup vs baseline: 1.7185x; 1.7185x over previous
//
#include <hip/hip_runtime.h>

#define SN 128
#define SPK 512

constexpr float GMIN  = 0.1f;
constexpr float PFRAC = 0.3f;
constexpr float GMAX  = 1.0f;

// Wave-synchronous lazy-decay kernel, 32 cells/lane, register walk (R8 base)
// + pooled-amplitude invariant: per-cell amplitude is NON-DECREASING across
// touches (a' - a = -0.3a + 0.27/C > 0 because v = C*a + GMIN <= 1), so
// pmax[slot] = running max of the slot's 4 cell amplitudes is exact, and a
// snapshot is just o[k] = C_r*pmax[k] + GMIN (pool commutes with the
// positive affine map). Untouched cells: pmax init = -GMIN gives u_r.
//
// Block = one 64-lane wave = (s, p, xq): x in [xq*16, xq*16+16), all 128 y.
// Lane: xp = lane>>3 (x-pair), yb = lane&7 (16-wide y chunk).
// Cells: a[j], j = (x&1)<<4 | (y&15);  v = C(n)*a + GMIN, C(n)=exp((ts0-ts[n])/TAU).
// Spike: a' = (1-PFRAC)*a + PFRAC*(GMAX-GMIN)/C(n).
//
// meta: bits 4-14 pos (p<<14|x<<7|y masked 0x7F70) | bit 15 owner-valid |
//       bits 16-20 jidx | bits 24-26 tt value | bit 31 snapshot flag.

__global__ __launch_bounds__(64, 2) void trace_kernel(
    const int*   __restrict__ event,   // (SN, SPK, 3) int32: x, y, pol
    const float* __restrict__ ts,      // (SN, SPK) f32, ascending
    const int*   __restrict__ tt,      // (SN, SPK) int32 in [0,8)
    const int*   __restrict__ length,  // (SN,) int32
    float*       __restrict__ out)     // (SN, 8, 2, 64, 64) f32
{
    const int wg   = blockIdx.x;
    const int s    = wg >> 4;
    const int p    = (wg >> 3) & 1;
    const int xq   = wg & 7;
    const int lane = threadIdx.x;      // 0..63

    const int   len = length[s];
    const float ts0 = ts[s * SPK];

    // ---- pass 1: load + pack per-step state (16 regs) ----
    unsigned meta[8]; float tsn[8];
#pragma unroll
    for (int r8 = 0; r8 < 8; ++r8) {
        int n = r8 * 64 + lane;
        int tv_ = tt[s * SPK + n];
        tsn[r8] = ts[s * SPK + n];
        const int* ev = event + (size_t)(s * SPK + n) * 3;
        int ex = ev[0], ey = ev[1], ep = ev[2];
        unsigned mw = (unsigned)tv_ << 24;
        bool ownerb = (n >= 1) && (n < len) && (ep == p) && ((ex >> 4) == xq);
        if (ownerb) {
            mw |= 0x8000u
                | ((unsigned)((p << 14) | (ex << 7) | ey) & 0x7F70u)
                | ((unsigned)(((ex & 1) << 4) | (ey & 15)) << 16);
        }
        meta[r8] = mw;
    }

    // ---- snlast per slot: reverse scan with uniform early-exit ----
    int snl[8];
#pragma unroll
    for (int r = 0; r < 8; ++r) {
        int f = -1;
#pragma unroll
        for (int rr = 7; rr >= 0; --rr) {
            if (f < 0) {   // wave-uniform guard: skip ballots once found
                unsigned long long m =
                    __ballot(((meta[rr] >> 24) & 7u) == (unsigned)r &&
                             (rr > 0 || lane > 0));
                if (m) f = rr * 64 + 63 - __clzll(m);
            }
        }
        snl[r] = f;
    }

    // ---- per-lane cell block ----
    const int xp     = lane >> 3;
    const int yb     = lane & 7;
    const int x_even = xq * 16 + 2 * xp;
    const unsigned mypat = (unsigned)((p << 14) | (x_even << 7) | (yb << 4));
    const int Xo = xq * 8 + xp;
    // output: base for rr=0 plus per-lane offset; snapshot r adds rr*8192
    float* const obase = out + (size_t)(((s * 8) * 2 + p) * 64 + Xo) * 64 + yb * 8;

    float a[32];
#pragma unroll
    for (int j = 0; j < 32; ++j) a[j] = -GMIN;             // v = 0 everywhere

    // init spike at n=0 (C(0)=1); reference SETS 0.27 -> amplitude 0.17
    bool own0 = false; int j0 = 0;
    {
        const int* ev0 = event + (size_t)s * SPK * 3;
        int x0 = ev0[0], y0 = ev0[1], p0 = ev0[2];
        unsigned pos0 = (unsigned)((p0 << 14) | (x0 << 7) | y0);
        if ((pos0 & 0x7F70u) == mypat) {
            own0 = true;
            j0 = ((x0 & 1) << 4) | (y0 & 15);
#pragma unroll
            for (int j = 0; j < 32; ++j)
                if (j == j0) a[j] = PFRAC * (GMAX - GMIN) - GMIN;
        }
    }

    // pooled running-max amplitudes (slot k pools cells {2k,2k+1,16+2k,17+2k})
    float pmax[8];
#pragma unroll
    for (int k = 0; k < 8; ++k) {
        bool hit = own0 && (k == ((j0 & 15) >> 1));
        pmax[k] = hit ? (PFRAC * (GMAX - GMIN) - GMIN) : -GMIN;
    }

    // ---- fused compaction + apply, 8 rounds of 64 steps ----
#pragma unroll
    for (int r8 = 0; r8 < 8; ++r8) {
        // scalar snapshot mask for this round (snl are wave-uniform)
        unsigned long long smask = 0ull;
#pragma unroll
        for (int r = 0; r < 8; ++r)
            if ((snl[r] >> 6) == r8) smask |= 1ull << (snl[r] & 63);

        bool psnap  = (smask >> lane) & 1ull;
        unsigned mw = meta[r8];
        bool powner = (mw >> 15) & 1u;
        bool pred   = psnap || powner;

        float myC = 0.0f, myCr = 0.0f;
        if (pred) {
            float d = (ts0 - tsn[r8]) * 0.01f;             // TAU = 100
            myC  = __expf(d);
            myCr = (PFRAC * (GMAX - GMIN)) * __expf(-d);
            if (psnap) mw |= 0x80000000u;
        }

        unsigned long long mask = __ballot(pred);
        while (mask) {
            int src = (int)__builtin_ctzll(mask);
            mask &= mask - 1;
            unsigned mwu = (unsigned)__builtin_amdgcn_readlane((int)mw, src);

            if (mwu & 0x8000u) {            // owner event (scalar guard)
                float Crs  = __int_as_float(
                    __builtin_amdgcn_readlane(__float_as_int(myCr), src));
                bool  own  = (mwu & 0x7F70u) == mypat;
                float coef = own ? (1.0f - PFRAC) : 1.0f;
                float addb = own ? Crs : 0.0f;
                switch ((mwu >> 16) & 31u) {   // uniform jidx; static pmax slot
#define OWN_CASE(k) case k:                                                   \
                    a[k] = fmaf(coef, a[k], addb);                            \
                    pmax[(k & 15) >> 1] = fmaxf(pmax[(k & 15) >> 1], a[k]);   \
                    break;
                    OWN_CASE(0)  OWN_CASE(1)  OWN_CASE(2)  OWN_CASE(3)
                    OWN_CASE(4)  OWN_CASE(5)  OWN_CASE(6)  OWN_CASE(7)
                    OWN_CASE(8)  OWN_CASE(9)  OWN_CASE(10) OWN_CASE(11)
                    OWN_CASE(12) OWN_CASE(13) OWN_CASE(14) OWN_CASE(15)
                    OWN_CASE(16) OWN_CASE(17) OWN_CASE(18) OWN_CASE(19)
                    OWN_CASE(20) OWN_CASE(21) OWN_CASE(22) OWN_CASE(23)
                    OWN_CASE(24) OWN_CASE(25) OWN_CASE(26) OWN_CASE(27)
                    OWN_CASE(28) OWN_CASE(29) OWN_CASE(30) OWN_CASE(31)
#undef OWN_CASE
                }
            }

            if ((int)mwu < 0) {             // snapshot (scalar guard)
                float C  = __int_as_float(
                    __builtin_amdgcn_readlane(__float_as_int(myC), src));
                int   rr = (int)((mwu >> 24) & 7u);
                float4 o1, o2;
                o1.x = fmaf(C, pmax[0], GMIN);
                o1.y = fmaf(C, pmax[1], GMIN);
                o1.z = fmaf(C, pmax[2], GMIN);
                o1.w = fmaf(C, pmax[3], GMIN);
                o2.x = fmaf(C, pmax[4], GMIN);
                o2.y = fmaf(C, pmax[5], GMIN);
                o2.z = fmaf(C, pmax[6], GMIN);
                o2.w = fmaf(C, pmax[7], GMIN);
                float* dst = obase + (size_t)rr * (2 * 64 * 64);
                *reinterpret_cast<float4*>(dst)     = o1;
                *reinterpret_cast<float4*>(dst + 4) = o2;
            }
        }
    }

    // ---- slots that never occur at n>=1: default snapshots ----
#pragma unroll
    for (int r = 0; r < 8; ++r) {
        if (snl[r] < 0) {
            float o[8];
#pragma unroll
            for (int k = 0; k < 8; ++k) {
                bool hit = (r == 0) && own0 && (k == ((j0 & 15) >> 1));
                o[k] = hit ? PFRAC * (GMAX - GMIN) : 0.0f;
            }
            float* dst = obase + (size_t)r * (2 * 64 * 64);
            *reinterpret_cast<float4*>(dst)     = make_float4(o[0], o[1], o[2], o[3]);
            *reinterpret_cast<float4*>(dst + 4) = make_float4(o[4], o[5], o[6], o[7]);
        }
    }
}

extern "C" void kernel_launch(void* const* d_in, const int* in_sizes, int n_in,
                              void* d_out, int out_size, void* d_ws, size_t ws_size,
                              hipStream_t stream) {
    const int*   event  = (const int*)  d_in[0];
    const float* ts     = (const float*)d_in[1];
    const int*   tt     = (const int*)  d_in[2];
    const int*   length = (const int*)  d_in[3];
    float*       out    = (float*)d_out;

    // 128 samples x 2 polarities x 8 x-chunks = 2048 one-wave blocks
    trace_kernel<<<dim3(SN * 2 * 8), dim3(64), 0, stream>>>(event, ts, tt, length, out);
}

// Round 13
// 27.053 us; speedup vs baseline: 1.8057x; 1.0508x over previous
//
#include <hip/hip_runtime.h>

#define SN 128
#define SPK 512

constexpr float GMIN  = 0.1f;
constexpr float PFRAC = 0.3f;
constexpr float GMAX  = 1.0f;

// Wave-synchronous lazy-decay kernel, 32 cells/lane, register walk (R8 exact).
// Block = one 64-lane wave = (s, p, xq): x in [xq*16, xq*16+16), all 128 y.
// Lane: xp = lane>>3 (x-pair), yb = lane&7 (16-wide y chunk).
// Cells: a[j], j = (x&1)<<4 | (y&15);  v = C(n)*a + GMIN, C(n)=exp((ts0-ts[n])/TAU).
// Spike: a' = (1-PFRAC)*a + PFRAC*(GMAX-GMIN)/C(n).
// Per 64-step round: ballot {owner events, surviving snapshots}, scalar-walk
// the mask broadcasting {meta, C, Cr} via readlane. Single-fma switch cases.
//
// meta: bits 4-14 pos (p<<14|x<<7|y masked 0x7F70) | bit 15 owner-valid |
//       bits 16-20 jidx | bits 24-26 tt value | bit 31 snapshot flag.

__global__ __launch_bounds__(64, 2) void trace_kernel(
    const int*   __restrict__ event,   // (SN, SPK, 3) int32: x, y, pol
    const float* __restrict__ ts,      // (SN, SPK) f32, ascending
    const int*   __restrict__ tt,      // (SN, SPK) int32 in [0,8)
    const int*   __restrict__ length,  // (SN,) int32
    float*       __restrict__ out)     // (SN, 8, 2, 64, 64) f32
{
    const int wg   = blockIdx.x;
    const int s    = wg >> 4;
    const int p    = (wg >> 3) & 1;
    const int xq   = wg & 7;
    const int lane = threadIdx.x;      // 0..63

    const int   len = length[s];
    const float ts0 = ts[s * SPK];

    // ---- pass 1: load + pack per-step state (16 regs) ----
    unsigned meta[8]; float tsn[8];
#pragma unroll
    for (int r8 = 0; r8 < 8; ++r8) {
        int n = r8 * 64 + lane;
        int tv_ = tt[s * SPK + n];
        tsn[r8] = ts[s * SPK + n];
        const int* ev = event + (size_t)(s * SPK + n) * 3;
        int ex = ev[0], ey = ev[1], ep = ev[2];
        unsigned mw = (unsigned)tv_ << 24;
        bool ownerb = (n >= 1) && (n < len) && (ep == p) && ((ex >> 4) == xq);
        if (ownerb) {
            mw |= 0x8000u
                | ((unsigned)((p << 14) | (ex << 7) | ey) & 0x7F70u)
                | ((unsigned)(((ex & 1) << 4) | (ey & 15)) << 16);
        }
        meta[r8] = mw;
    }

    // ---- snlast per slot: reverse scan with uniform early-exit ----
    int snl[8];
#pragma unroll
    for (int r = 0; r < 8; ++r) {
        int f = -1;
#pragma unroll
        for (int rr = 7; rr >= 0; --rr) {
            if (f < 0) {   // wave-uniform guard: skip ballots once found
                unsigned long long m =
                    __ballot(((meta[rr] >> 24) & 7u) == (unsigned)r &&
                             (rr > 0 || lane > 0));
                if (m) f = rr * 64 + 63 - __clzll(m);
            }
        }
        snl[r] = f;
    }

    // ---- per-lane cell block ----
    const int xp     = lane >> 3;
    const int yb     = lane & 7;
    const int x_even = xq * 16 + 2 * xp;
    const unsigned mypat = (unsigned)((p << 14) | (x_even << 7) | (yb << 4));
    const int Xo = xq * 8 + xp;
    // output base for snapshot slot 0; slot r adds r*2*64*64
    float* const obase = out + (size_t)(((s * 8) * 2 + p) * 64 + Xo) * 64 + yb * 8;

    float a[32];
#pragma unroll
    for (int j = 0; j < 32; ++j) a[j] = -GMIN;             // v = 0 everywhere

    // init spike at n=0 (C(0)=1); uniform-address loads -> scalar
    bool own0 = false; int j0 = 0;
    {
        const int* ev0 = event + (size_t)s * SPK * 3;
        int x0 = ev0[0], y0 = ev0[1], p0 = ev0[2];
        unsigned pos0 = (unsigned)((p0 << 14) | (x0 << 7) | y0);
        if ((pos0 & 0x7F70u) == mypat) {
            own0 = true;
            j0 = ((x0 & 1) << 4) | (y0 & 15);
#pragma unroll
            for (int j = 0; j < 32; ++j)
                if (j == j0) a[j] = PFRAC * (GMAX - GMIN) - GMIN;
        }
    }

    // ---- fused compaction + apply, 8 rounds of 64 steps ----
#pragma unroll
    for (int r8 = 0; r8 < 8; ++r8) {
        int n = r8 * 64 + lane;

        bool psnap = false;
#pragma unroll
        for (int r = 0; r < 8; ++r) psnap |= (n == snl[r]);
        unsigned mw = meta[r8];
        bool powner = (mw >> 15) & 1u;
        bool pred   = psnap || powner;

        float myC = 0.0f, myCr = 0.0f;
        if (pred) {
            float d = (ts0 - tsn[r8]) * 0.01f;             // TAU = 100
            myC  = __expf(d);
            myCr = (PFRAC * (GMAX - GMIN)) * __expf(-d);
            if (psnap) mw |= 0x80000000u;
        }

        unsigned long long mask = __ballot(pred);
        while (mask) {
            int src = (int)__builtin_ctzll(mask);
            mask &= mask - 1;
            unsigned mwu = (unsigned)__builtin_amdgcn_readlane((int)mw, src);
            int      Cri = __builtin_amdgcn_readlane(__float_as_int(myCr), src);

            if (mwu & 0x8000u) {            // owner event (scalar guard)
                bool  own  = (mwu & 0x7F70u) == mypat;
                float coef = own ? (1.0f - PFRAC) : 1.0f;
                float addb = own ? __int_as_float(Cri) : 0.0f;
                switch ((mwu >> 16) & 31u) {     // uniform jidx
#define OWN_CASE(k) case k: a[k] = fmaf(coef, a[k], addb); break;
                    OWN_CASE(0)  OWN_CASE(1)  OWN_CASE(2)  OWN_CASE(3)
                    OWN_CASE(4)  OWN_CASE(5)  OWN_CASE(6)  OWN_CASE(7)
                    OWN_CASE(8)  OWN_CASE(9)  OWN_CASE(10) OWN_CASE(11)
                    OWN_CASE(12) OWN_CASE(13) OWN_CASE(14) OWN_CASE(15)
                    OWN_CASE(16) OWN_CASE(17) OWN_CASE(18) OWN_CASE(19)
                    OWN_CASE(20) OWN_CASE(21) OWN_CASE(22) OWN_CASE(23)
                    OWN_CASE(24) OWN_CASE(25) OWN_CASE(26) OWN_CASE(27)
                    OWN_CASE(28) OWN_CASE(29) OWN_CASE(30) OWN_CASE(31)
#undef OWN_CASE
                }
            }

            if ((int)mwu < 0) {             // snapshot (scalar guard)
                float C  = __int_as_float(
                    __builtin_amdgcn_readlane(__float_as_int(myC), src));
                int   rr = (int)((mwu >> 24) & 7u);
                float o[8];
#pragma unroll
                for (int k = 0; k < 8; ++k) {
                    float v0 = fmaf(C, a[2 * k],      GMIN);
                    float v1 = fmaf(C, a[2 * k + 1],  GMIN);
                    float v2 = fmaf(C, a[16 + 2 * k], GMIN);
                    float v3 = fmaf(C, a[17 + 2 * k], GMIN);
                    o[k] = fmaxf(fmaxf(fmaxf(v0, v1), v2), v3);
                }
                float* dst = obase + (size_t)rr * (2 * 64 * 64);
                *reinterpret_cast<float4*>(dst)     = make_float4(o[0], o[1], o[2], o[3]);
                *reinterpret_cast<float4*>(dst + 4) = make_float4(o[4], o[5], o[6], o[7]);
            }
        }
    }

    // ---- slots that never occur at n>=1: default snapshots ----
#pragma unroll
    for (int r = 0; r < 8; ++r) {
        if (snl[r] < 0) {
            float o[8];
#pragma unroll
            for (int k = 0; k < 8; ++k) {
                bool hit = (r == 0) && own0 && (k == ((j0 & 15) >> 1));
                o[k] = hit ? PFRAC * (GMAX - GMIN) : 0.0f;
            }
            float* dst = obase + (size_t)r * (2 * 64 * 64);
            *reinterpret_cast<float4*>(dst)     = make_float4(o[0], o[1], o[2], o[3]);
            *reinterpret_cast<float4*>(dst + 4) = make_float4(o[4], o[5], o[6], o[7]);
        }
    }
}

extern "C" void kernel_launch(void* const* d_in, const int* in_sizes, int n_in,
                              void* d_out, int out_size, void* d_ws, size_t ws_size,
                              hipStream_t stream) {
    const int*   event  = (const int*)  d_in[0];
    const float* ts     = (const float*)d_in[1];
    const int*   tt     = (const int*)  d_in[2];
    const int*   length = (const int*)  d_in[3];
    float*       out    = (float*)d_out;

    // 128 samples x 2 polarities x 8 x-chunks = 2048 one-wave blocks
    trace_kernel<<<dim3(SN * 2 * 8), dim3(64), 0, stream>>>(event, ts, tt, length, out);
}